// Round 9
// baseline (19434.869 us; speedup 1.0000x reference)
//
#include <hip/hip_runtime.h>

typedef short short8 __attribute__((ext_vector_type(8)));
typedef float floatx4 __attribute__((ext_vector_type(4)));
typedef unsigned short u16;
typedef unsigned int u32;

__device__ __forceinline__ float bits2f(u16 u) {
  union { unsigned int i; float f; } w;
  w.i = ((unsigned int)u) << 16;
  return w.f;
}

__device__ __forceinline__ u16 f2bf(float f) {
  union { float f; unsigned int i; } w;
  w.f = f;
  unsigned int x = w.i;
  unsigned int r = (x + 0x7FFFu + ((x >> 16) & 1u)) >> 16;  // RNE
  return (u16)r;
}

// tanh-form GELU via sigmoid; max abs dev from exact ~3e-4
__device__ __forceinline__ float gelu_f(float x) {
  float t = x * (1.5957691216057308f + 0.07135481283247914f * x * x);
  return x / (1.0f + __expf(-t));
}

// fragment-major index: array [R/16 groups][K/8 octets][16 lanes][8 elems]
__device__ __forceinline__ size_t fidx(int row, int col, int Kd) {
  return (size_t)(row >> 4) * ((size_t)Kd * 16) + (size_t)(col >> 3) * 128 +
         ((row & 15) << 3) + (col & 7);
}
__device__ __forceinline__ size_t fidx768(int row, int col) {
  return (size_t)(row >> 4) * 12288 + (size_t)(col >> 3) * 128 +
         ((row & 15) << 3) + (col & 7);
}

// ------------- fused prep: cvt x->xb(frag), pack bias, W->frag-major ---------
// blocks: [0,3072) cvt | [3072,3081) bias | [3081,5385) Wq/Wk/Wv/Wo | [5385,7689) W1
__global__ __launch_bounds__(256) void prep_kernel(
    const float* __restrict__ x, u16* __restrict__ xb,
    const float* __restrict__ bq, const float* __restrict__ bk,
    const float* __restrict__ bv, float* __restrict__ biasqkv,
    const float* __restrict__ Wq, const float* __restrict__ Wk,
    const float* __restrict__ Wv, const float* __restrict__ Wo,
    const float* __restrict__ W1,
    u16* __restrict__ Bqkv, u16* __restrict__ Bo, u16* __restrict__ B1) {
  __shared__ float tile[32][33];
  int bid = blockIdx.x;
  int tid = threadIdx.x;
  if (bid < 3072) {  // cvt: one k-octet per thread, stored frag-major
    int i = bid * 256 + tid;          // octet index over row-major x
    const float4* p = (const float4*)x + (size_t)i * 2;
    float4 a = p[0], b = p[1];
    u16 t[8] = {f2bf(a.x), f2bf(a.y), f2bf(a.z), f2bf(a.w),
                f2bf(b.x), f2bf(b.y), f2bf(b.z), f2bf(b.w)};
    int row = i / 96;                 // 96 octets per 768-row
    int oct = i - row * 96;
    size_t fa = (size_t)(row >> 4) * 12288 + (size_t)oct * 128 + ((row & 15) << 3);
    *(int4*)(xb + fa) = *(const int4*)t;
    return;
  }
  if (bid < 3081) {  // bias pack
    int i = (bid - 3072) * 256 + tid;
    biasqkv[i] = (i < 768) ? bq[i] : (i < 1536 ? bk[i - 768] : bv[i - 1536]);
    return;
  }
  const float* W;
  u16* WT;
  int N, bx, by, n_off;
  if (bid < 5385) {  // 4 square transposes (768x768), 576 blocks each
    int s = bid - 3081;
    int wsel = s / 576;
    int r = s - wsel * 576;
    N = 768; bx = r % 24; by = r / 24;
    if (wsel < 3) { W = (wsel == 0) ? Wq : (wsel == 1 ? Wk : Wv); WT = Bqkv; n_off = wsel * 768; }
    else          { W = Wo; WT = Bo; n_off = 0; }
  } else {  // W1 [768,3072] -> B1 frag [192][96][16][8]
    int r = bid - 5385;
    N = 3072; bx = r % 96; by = r / 96;
    W = W1; WT = B1; n_off = 0;
  }
  int tx = tid & 31, ty = tid >> 5;
  int n0 = bx * 32, k0 = by * 32;
#pragma unroll
  for (int i = 0; i < 4; i++)
    tile[ty + i * 8][tx] = W[(size_t)(k0 + ty + i * 8) * N + n0 + tx];
  __syncthreads();
#pragma unroll
  for (int i = 0; i < 4; i++) {
    int n = n_off + n0 + ty + i * 8;
    int k = k0 + tx;
    WT[fidx(n, k, 768)] = f2bf(tile[tx][ty + i * 8]);  // weights: K dim = 768
  }
}

// ------------- W2 [3072,768] -> B2 frag [48][384][16][8] ---------------------
__global__ __launch_bounds__(256) void transpose_k(const float* __restrict__ W,
                                                   u16* __restrict__ WT,
                                                   int K, int N) {
  __shared__ float tile[32][33];
  int tx = threadIdx.x & 31;
  int ty = threadIdx.x >> 5;
  int n0 = blockIdx.x * 32;
  int k0 = blockIdx.y * 32;
#pragma unroll
  for (int i = 0; i < 4; i++)
    tile[ty + i * 8][tx] = W[(size_t)(k0 + ty + i * 8) * N + n0 + tx];
  __syncthreads();
#pragma unroll
  for (int i = 0; i < 4; i++) {
    int n = n0 + ty + i * 8;
    int k = k0 + tx;
    WT[fidx(n, k, K)] = f2bf(tile[tx][ty + i * 8]);
  }
}

// ------------- LDS-free fragment GEMM: C = A @ B^T + bias -------------------
// A frag-major [M/16][Ka/8][16][8], B frag-major [N/16][Ka/8][16][8].
// Each wave loads its MFMA fragments straight from global (L2-resident, fully
// coalesced: base + lane*16B), 2-stage register pipeline, NO LDS, NO barriers.
// cmode: 0 = row-major bf16, 1 = row-major fp32, 2 = frag-major bf16.
// XCD swizzle requires gridDim.y==64, gridDim.x%6==0.
template <int BN>
__global__ __launch_bounds__(256) void gemm_frag(
    const u16* __restrict__ Af, const u16* __restrict__ Bf, int Ka,
    const float* __restrict__ bias, void* __restrict__ Cv,
    int N, int act, int cmode) {
  int tid = threadIdx.x;
  int wave = tid >> 6, lane = tid & 63;
  int l15 = lane & 15, quad = lane >> 4;

  int nb = gridDim.x;
  int lin = blockIdx.y * nb + blockIdx.x;
  int xcd = lin & 7, i = lin >> 3;
  int grp = i / 48, rem = i - grp * 48;
  int nblk = grp * 6 + rem % 6;
  int mblk = (xcd << 3) + rem / 6;
  int m0 = mblk * 128, n0 = nblk * BN;

  constexpr int MT = (BN == 128) ? 4 : 2;
  constexpr int NT = 4;
  int wm = (BN == 128) ? (wave & 1) * 64 : wave * 32;
  int wn = (BN == 128) ? (wave >> 1) * 64 : 0;

  size_t gs = (size_t)Ka * 16;  // elems per 16-row group
  const u16* Ab = Af + (size_t)((m0 + wm) >> 4) * gs + lane * 8;
  const u16* Bb = Bf + (size_t)((n0 + wn) >> 4) * gs + lane * 8;

  floatx4 acc[MT][NT];
#pragma unroll
  for (int mi = 0; mi < MT; mi++)
#pragma unroll
    for (int ni = 0; ni < NT; ni++) acc[mi][ni] = (floatx4){0.f, 0.f, 0.f, 0.f};

  short8 a_[2][MT], b_[2][NT];
  {
#pragma unroll
    for (int mi = 0; mi < MT; mi++) a_[0][mi] = *(const short8*)(Ab + mi * gs);
#pragma unroll
    for (int ni = 0; ni < NT; ni++) b_[0][ni] = *(const short8*)(Bb + ni * gs);
  }
  for (int k0 = 0; k0 < Ka; k0 += 32) {
    int cur = (k0 >> 5) & 1;
    if (k0 + 32 < Ka) {
      size_t off = (size_t)(k0 + 32) * 16;
#pragma unroll
      for (int mi = 0; mi < MT; mi++)
        a_[cur ^ 1][mi] = *(const short8*)(Ab + mi * gs + off);
#pragma unroll
      for (int ni = 0; ni < NT; ni++)
        b_[cur ^ 1][ni] = *(const short8*)(Bb + ni * gs + off);
    }
#pragma unroll
    for (int mi = 0; mi < MT; mi++)
#pragma unroll
      for (int ni = 0; ni < NT; ni++)
        acc[mi][ni] = __builtin_amdgcn_mfma_f32_16x16x32_bf16(
            a_[cur][mi], b_[cur][ni], acc[mi][ni], 0, 0, 0);
  }

#pragma unroll
  for (int mi = 0; mi < MT; mi++) {
#pragma unroll
    for (int ni = 0; ni < NT; ni++) {
      int col = n0 + wn + ni * 16 + l15;
      float bv = bias[col];
#pragma unroll
      for (int r = 0; r < 4; r++) {
        int row = m0 + wm + mi * 16 + quad * 4 + r;
        float v = acc[mi][ni][r] + bv;
        if (act == 1) v = gelu_f(v);
        if (cmode == 0)      ((u16*)Cv)[(size_t)row * N + col] = f2bf(v);
        else if (cmode == 1) ((float*)Cv)[(size_t)row * N + col] = v;
        else                 ((u16*)Cv)[fidx(row, col, N)] = f2bf(v);
      }
    }
  }
}

// ------------- flash-style MFMA attention: qkv row-major -> ctxf frag --------
__global__ __launch_bounds__(256) void attn_kernel(const u16* __restrict__ qkv,
                                                   u16* __restrict__ ctxf) {
  __shared__ __align__(16) u16 Qs[64][72];
  __shared__ __align__(16) u16 Ks[64][72];
  __shared__ __align__(16) u16 Vt[64][72];   // [d][key]
  __shared__ __align__(16) u16 Ps[4][16][72];

  const int LD = 2304;
  int bh = blockIdx.x;  // 0..191
  int b = bh / 12;
  int h = bh - b * 12;
  int q0 = blockIdx.y * 64;
  size_t base = (size_t)b * 512 * LD + (size_t)h * 64;
  const u16* qg = qkv + base;
  const u16* kg = qkv + base + 768;
  const u16* vg = qkv + base + 1536;
  int tid = threadIdx.x;
  int wave = tid >> 6;
  int lane = tid & 63;
  int l15 = lane & 15;
  int quad = lane >> 4;

  int srow = tid >> 2;
  int sd = (tid & 3) * 16;

  {
    const u16* qp = qg + (size_t)(q0 + srow) * LD + sd;
    *(int4*)&Qs[srow][sd]     = *(const int4*)qp;
    *(int4*)&Qs[srow][sd + 8] = *(const int4*)(qp + 8);
  }
  __syncthreads();

  short8 aQ[2];
#pragma unroll
  for (int k = 0; k < 2; k++)
    aQ[k] = *(const short8*)&Qs[16 * wave + l15][k * 32 + quad * 8];

  floatx4 O[4];
  float m_r[4], l_r[4];
#pragma unroll
  for (int nt = 0; nt < 4; nt++) O[nt] = (floatx4){0.f, 0.f, 0.f, 0.f};
#pragma unroll
  for (int r = 0; r < 4; r++) { m_r[r] = -1e30f; l_r[r] = 0.f; }

  const float cst = 0.18033688011112042f;  // (1/8) * log2(e)

  for (int c = 0; c < 8; c++) {
    const u16* kp = kg + (size_t)(c * 64 + srow) * LD + sd;
    const u16* vp = vg + (size_t)(c * 64 + srow) * LD + sd;
    int4 kv0 = *(const int4*)kp;
    int4 kv1 = *(const int4*)(kp + 8);
    int4 vv0 = *(const int4*)vp;
    int4 vv1 = *(const int4*)(vp + 8);
    __syncthreads();
    *(int4*)&Ks[srow][sd]     = kv0;
    *(int4*)&Ks[srow][sd + 8] = kv1;
    {
      u16 tv[16];
      *(int4*)tv = vv0;
      *(int4*)(tv + 8) = vv1;
#pragma unroll
      for (int j = 0; j < 16; j++) Vt[sd + j][srow] = tv[j];
    }
    __syncthreads();

    floatx4 S[4];
#pragma unroll
    for (int nt = 0; nt < 4; nt++) {
      floatx4 s = {0.f, 0.f, 0.f, 0.f};
      short8 bK0 = *(const short8*)&Ks[nt * 16 + l15][quad * 8];
      short8 bK1 = *(const short8*)&Ks[nt * 16 + l15][32 + quad * 8];
      s = __builtin_amdgcn_mfma_f32_16x16x32_bf16(aQ[0], bK0, s, 0, 0, 0);
      s = __builtin_amdgcn_mfma_f32_16x16x32_bf16(aQ[1], bK1, s, 0, 0, 0);
      S[nt] = s;
    }

#pragma unroll
    for (int r = 0; r < 4; r++) {
      float s0 = S[0][r] * cst, s1 = S[1][r] * cst;
      float s2 = S[2][r] * cst, s3 = S[3][r] * cst;
      float mr = fmaxf(fmaxf(s0, s1), fmaxf(s2, s3));
#pragma unroll
      for (int off = 1; off < 16; off <<= 1) mr = fmaxf(mr, __shfl_xor(mr, off, 16));
      float m_new = fmaxf(m_r[r], mr);
      float alpha = exp2f(m_r[r] - m_new);
      m_r[r] = m_new;
      float p0 = exp2f(s0 - m_new), p1 = exp2f(s1 - m_new);
      float p2 = exp2f(s2 - m_new), p3 = exp2f(s3 - m_new);
      S[0][r] = p0; S[1][r] = p1; S[2][r] = p2; S[3][r] = p3;
      float sum = p0 + p1 + p2 + p3;
#pragma unroll
      for (int off = 1; off < 16; off <<= 1) sum += __shfl_xor(sum, off, 16);
      l_r[r] = l_r[r] * alpha + sum;
      O[0][r] *= alpha; O[1][r] *= alpha; O[2][r] *= alpha; O[3][r] *= alpha;
    }

#pragma unroll
    for (int nt = 0; nt < 4; nt++)
#pragma unroll
      for (int r = 0; r < 4; r++)
        Ps[wave][quad * 4 + r][nt * 16 + l15] = f2bf(S[nt][r]);

    short8 aP[2];
#pragma unroll
    for (int k = 0; k < 2; k++)
      aP[k] = *(const short8*)&Ps[wave][l15][k * 32 + quad * 8];

#pragma unroll
    for (int nt = 0; nt < 4; nt++) {
      short8 bV0 = *(const short8*)&Vt[nt * 16 + l15][quad * 8];
      short8 bV1 = *(const short8*)&Vt[nt * 16 + l15][32 + quad * 8];
      O[nt] = __builtin_amdgcn_mfma_f32_16x16x32_bf16(aP[0], bV0, O[nt], 0, 0, 0);
      O[nt] = __builtin_amdgcn_mfma_f32_16x16x32_bf16(aP[1], bV1, O[nt], 0, 0, 0);
    }
  }

  // epilogue: ctx written FRAG-MAJOR (A-operand of the Wo GEMM)
#pragma unroll
  for (int r = 0; r < 4; r++) {
    float inv = 1.0f / l_r[r];
    int grow = b * 512 + q0 + 16 * wave + quad * 4 + r;
#pragma unroll
    for (int nt = 0; nt < 4; nt++) {
      int col = h * 64 + nt * 16 + l15;
      ctxf[fidx768(grow, col)] = f2bf(O[nt][r] * inv);
    }
  }
}

// ------------- LN1: hb(frag bf16) = LN(aob_row_bf16 + x_row_f32) -------------
__global__ __launch_bounds__(256) void ln1_kernel(
    const u16* __restrict__ a, const float* __restrict__ r,
    const float* __restrict__ g, const float* __restrict__ bb,
    u16* __restrict__ out) {
  int row = blockIdx.x;
  int tid = threadIdx.x;
  __shared__ float red[4];
  const u16* ap = a + (size_t)row * 768;
  const float* rp = r + (size_t)row * 768;
  float x0 = bits2f(ap[tid]) + rp[tid];
  float x1 = bits2f(ap[tid + 256]) + rp[tid + 256];
  float x2 = bits2f(ap[tid + 512]) + rp[tid + 512];
  float s = x0 + x1 + x2;
#pragma unroll
  for (int off = 32; off > 0; off >>= 1) s += __shfl_xor(s, off, 64);
  if ((tid & 63) == 0) red[tid >> 6] = s;
  __syncthreads();
  float mu = (red[0] + red[1] + red[2] + red[3]) * (1.0f / 768.0f);
  float d0 = x0 - mu, d1 = x1 - mu, d2 = x2 - mu;
  float vs = d0 * d0 + d1 * d1 + d2 * d2;
#pragma unroll
  for (int off = 32; off > 0; off >>= 1) vs += __shfl_xor(vs, off, 64);
  __syncthreads();
  if ((tid & 63) == 0) red[tid >> 6] = vs;
  __syncthreads();
  float var = (red[0] + red[1] + red[2] + red[3]) * (1.0f / 768.0f);
  float rstd = rsqrtf(var + 1e-12f);
  out[fidx768(row, tid)]       = f2bf(d0 * rstd * g[tid] + bb[tid]);
  out[fidx768(row, tid + 256)] = f2bf(d1 * rstd * g[tid + 256] + bb[tid + 256]);
  out[fidx768(row, tid + 512)] = f2bf(d2 * rstd * g[tid + 512] + bb[tid + 512]);
}

// ------------- LN2: out_f32(row) = LN(a_f32_row + hb_frag_bf16), in-place ----
__global__ __launch_bounds__(256) void ln2_kernel(
    const float* __restrict__ a, const u16* __restrict__ rfrag,
    const float* __restrict__ g, const float* __restrict__ bb,
    float* __restrict__ out) {
  int row = blockIdx.x;
  int tid = threadIdx.x;
  __shared__ float red[4];
  const float* ap = a + (size_t)row * 768;
  float x0 = ap[tid] + bits2f(rfrag[fidx768(row, tid)]);
  float x1 = ap[tid + 256] + bits2f(rfrag[fidx768(row, tid + 256)]);
  float x2 = ap[tid + 512] + bits2f(rfrag[fidx768(row, tid + 512)]);
  float s = x0 + x1 + x2;
#pragma unroll
  for (int off = 32; off > 0; off >>= 1) s += __shfl_xor(s, off, 64);
  if ((tid & 63) == 0) red[tid >> 6] = s;
  __syncthreads();
  float mu = (red[0] + red[1] + red[2] + red[3]) * (1.0f / 768.0f);
  float d0 = x0 - mu, d1 = x1 - mu, d2 = x2 - mu;
  float vs = d0 * d0 + d1 * d1 + d2 * d2;
#pragma unroll
  for (int off = 32; off > 0; off >>= 1) vs += __shfl_xor(vs, off, 64);
  __syncthreads();
  if ((tid & 63) == 0) red[tid >> 6] = vs;
  __syncthreads();
  float var = (red[0] + red[1] + red[2] + red[3]) * (1.0f / 768.0f);
  float rstd = rsqrtf(var + 1e-12f);
  size_t o = (size_t)row * 768;
  out[o + tid]       = d0 * rstd * g[tid] + bb[tid];
  out[o + tid + 256] = d1 * rstd * g[tid + 256] + bb[tid + 256];
  out[o + tid + 512] = d2 * rstd * g[tid + 512] + bb[tid + 512];
}

extern "C" void kernel_launch(void* const* d_in, const int* in_sizes, int n_in,
                              void* d_out, int out_size, void* d_ws, size_t ws_size,
                              hipStream_t stream) {
  (void)in_sizes; (void)n_in; (void)out_size; (void)ws_size;
  const float* x    = (const float*)d_in[0];
  const float* Wq   = (const float*)d_in[1];
  const float* bq   = (const float*)d_in[2];
  const float* Wk   = (const float*)d_in[3];
  const float* bk   = (const float*)d_in[4];
  const float* Wv   = (const float*)d_in[5];
  const float* bv   = (const float*)d_in[6];
  const float* Wo   = (const float*)d_in[7];
  const float* bo   = (const float*)d_in[8];
  const float* ln1g = (const float*)d_in[9];
  const float* ln1b = (const float*)d_in[10];
  const float* W1   = (const float*)d_in[11];
  const float* b1   = (const float*)d_in[12];
  const float* W2   = (const float*)d_in[13];
  const float* b2   = (const float*)d_in[14];
  const float* ln2g = (const float*)d_in[15];
  const float* ln2b = (const float*)d_in[16];

  const int M = 16 * 512, H = 768, FF = 3072;
  const size_t MH = (size_t)M * H;
  const size_t HH = (size_t)H * H;

  // ws (u16 elems):
  // [0,MH)        xb (frag)  -> ctxf (frag) -> (part of ffn1)
  // [MH,4MH)      qkv (row-major [M,2304]) -> (part of ffn1)
  // [0,4MH)       ffn1 (frag, after qkv/ctxf dead)
  // [4MH,5MH)     aob (row bf16)
  // [5MH,6MH)     hb (frag)  — live until ln2
  // [6MH,6MH+3HH) Bqkv frag  -> B2 frag (4HH, over Bqkv+Bo after Wo GEMM)
  // [6MH+3HH,+HH) Bo frag
  // [6MH+4HH,+4HH) B1 frag
  // biasqkv floats after B1
  u16* ws   = (u16*)d_ws;
  u16* xb   = ws;
  u16* qkv  = ws + MH;
  u16* ctxf = ws;
  u16* ffn1 = ws;
  u16* aob  = ws + 4 * MH;
  u16* hb   = ws + 5 * MH;
  u16* Bqkv = ws + 6 * MH;
  u16* Bo   = Bqkv + 3 * HH;
  u16* B1   = Bqkv + 4 * HH;
  u16* B2   = Bqkv;
  float* biasqkv = (float*)(B1 + 4 * HH);
  float* outf = (float*)d_out;

  dim3 tb(256);
  prep_kernel<<<dim3(7689), tb, 0, stream>>>(x, xb, bq, bk, bv, biasqkv,
                                             Wq, Wk, Wv, Wo, W1, Bqkv, Bo, B1);

  // QKV: qkv[M,2304] = xb @ Bqkv^T (row-major C for attention)
  gemm_frag<128><<<dim3(18, 64), tb, 0, stream>>>(
      xb, Bqkv, H, biasqkv, qkv, 2304, 0, 0);

  attn_kernel<<<dim3(192, 8), tb, 0, stream>>>(qkv, ctxf);

  // Wo: aob[M,768] = ctxf @ Bo^T (row-major C for ln1)
  gemm_frag<64><<<dim3(12, 64), tb, 0, stream>>>(
      ctxf, Bo, H, bo, aob, H, 0, 0);
  ln1_kernel<<<dim3(M), tb, 0, stream>>>(aob, x, ln1g, ln1b, hb);

  transpose_k<<<dim3(H / 32, FF / 32), tb, 0, stream>>>(W2, B2, FF, H);

  // FFN1: ffn1[M,3072] = hb @ B1^T, GELU, frag-major C
  gemm_frag<128><<<dim3(24, 64), tb, 0, stream>>>(
      hb, B1, H, b1, ffn1, FF, 1, 2);
  // FFN2: outf[M,768] = ffn1 @ B2^T, row-major fp32 C
  gemm_frag<64><<<dim3(12, 64), tb, 0, stream>>>(
      ffn1, B2, FF, b2, outf, H, 0, 1);
  ln2_kernel<<<dim3(M), tb, 0, stream>>>(outf, hb, ln2g, ln2b, outf);
}